// Round 17
// baseline (473.037 us; speedup 1.0000x reference)
//
#include <hip/hip_runtime.h>
#include <hip/hip_fp16.h>
#include <cstdint>
#include <cstdio>

#define NROW 4096
#define DMODEL 1024
#define DFF_ 4096

typedef _Float16 f16;
typedef _Float16 f16x4 __attribute__((ext_vector_type(4)));
typedef _Float16 f16x8 __attribute__((ext_vector_type(8)));
typedef float f32x4 __attribute__((ext_vector_type(4)));

__device__ __forceinline__ void g2l16(const void* g, void* l) {
  __builtin_amdgcn_global_load_lds((const __attribute__((address_space(1))) void*)g,
                                   (__attribute__((address_space(3))) void*)l,
                                   16, 0, 0);
}

// Bijective XCD-chunked block swizzle (T1). Requires nwg%8==0.
__device__ __forceinline__ int xcd_swz16() {
  const int bid = blockIdx.y * gridDim.x + blockIdx.x;
  const int nwg = gridDim.x * gridDim.y;
  return (bid & 7) * (nwg >> 3) + (bid >> 3);
}

// ---------------- elementwise converts ----------------
__global__ __launch_bounds__(256) void cvt_f32_f16(const float* __restrict__ in,
                                                   f16* __restrict__ out, long n4) {
  for (long i = (long)blockIdx.x * blockDim.x + threadIdx.x; i < n4;
       i += (long)gridDim.x * blockDim.x) {
    float4 a = ((const float4*)in)[i];
    f16x4 h = {(f16)a.x, (f16)a.y, (f16)a.z, (f16)a.w};
    ((f16x4*)out)[i] = h;
  }
}

// k16 = f16(xe + pos); xe16 = f16(xe)
__global__ __launch_bounds__(256) void add_cvt(const float* __restrict__ xe,
                                               const float* __restrict__ pos,
                                               f16* __restrict__ k16,
                                               f16* __restrict__ xe16, long n4) {
  for (long i = (long)blockIdx.x * blockDim.x + threadIdx.x; i < n4;
       i += (long)gridDim.x * blockDim.x) {
    float4 a = ((const float4*)xe)[i];
    float4 p = ((const float4*)pos)[i];
    f16x4 k = {(f16)(a.x + p.x), (f16)(a.y + p.y), (f16)(a.z + p.z), (f16)(a.w + p.w)};
    f16x4 v = {(f16)a.x, (f16)a.y, (f16)a.z, (f16)a.w};
    ((f16x4*)k16)[i] = k;
    ((f16x4*)xe16)[i] = v;
  }
}

// ---------------- layernorm (one block per row of 1024) ----------------
__global__ __launch_bounds__(256) void ln_row(const float* __restrict__ x,
                                              const float* __restrict__ g,
                                              const float* __restrict__ b,
                                              const float* __restrict__ pos,
                                              f16* __restrict__ nout,
                                              f16* __restrict__ qout) {
  const int row = blockIdx.x, tid = threadIdx.x;
  const float4 xv = ((const float4*)(x + (long)row * DMODEL))[tid];
  float s = xv.x + xv.y + xv.z + xv.w;
  float ss = xv.x * xv.x + xv.y * xv.y + xv.z * xv.z + xv.w * xv.w;
  for (int o = 32; o; o >>= 1) { s += __shfl_xor(s, o); ss += __shfl_xor(ss, o); }
  __shared__ float rs[4], rss[4];
  const int wid = tid >> 6, lane = tid & 63;
  if (!lane) { rs[wid] = s; rss[wid] = ss; }
  __syncthreads();
  s = rs[0] + rs[1] + rs[2] + rs[3];
  ss = rss[0] + rss[1] + rss[2] + rss[3];
  const float mean = s * (1.f / DMODEL);
  const float var = ss * (1.f / DMODEL) - mean * mean;
  const float rstd = rsqrtf(var + 1e-5f);
  const float4 gv = ((const float4*)g)[tid];
  const float4 bv = ((const float4*)b)[tid];
  float4 nv;
  nv.x = (xv.x - mean) * rstd * gv.x + bv.x;
  nv.y = (xv.y - mean) * rstd * gv.y + bv.y;
  nv.z = (xv.z - mean) * rstd * gv.z + bv.z;
  nv.w = (xv.w - mean) * rstd * gv.w + bv.w;
  if (nout) {
    f16x4 h = {(f16)nv.x, (f16)nv.y, (f16)nv.z, (f16)nv.w};
    *(f16x4*)&nout[(long)row * DMODEL + tid * 4] = h;
  }
  float4 pv = {0.f, 0.f, 0.f, 0.f};
  if (pos) pv = ((const float4*)(pos + (long)row * DMODEL))[tid];
  f16x4 q = {(f16)(nv.x + pv.x), (f16)(nv.y + pv.y), (f16)(nv.z + pv.z), (f16)(nv.w + pv.w)};
  *(f16x4*)&qout[(long)row * DMODEL + tid * 4] = q;
}

// ---------------- fp16 transpose: in [R][C] -> out [C][R], 64x64 tiles ----------------
__global__ __launch_bounds__(256) void transpose_h(const f16* __restrict__ in,
                                                   f16* __restrict__ out, int R, int C) {
  __shared__ f16 t[64][72];
  const int tid = threadIdx.x;
  const int r0 = blockIdx.y * 64, c0 = blockIdx.x * 64;
  const int tr = tid >> 4, tc = (tid & 15) * 4;
#pragma unroll
  for (int rr = 0; rr < 4; rr++) {
    int row = rr * 16 + tr;
    f16x4 v = *(const f16x4*)&in[(long)(r0 + row) * C + c0 + tc];
    *(f16x4*)&t[row][tc] = v;
  }
  __syncthreads();
#pragma unroll
  for (int rr = 0; rr < 4; rr++) {
    int row = rr * 16 + tr;
    f16x4 o = {t[tc + 0][row], t[tc + 1][row], t[tc + 2][row], t[tc + 3][row]};
    *(f16x4*)&out[(long)(c0 + row) * R + r0 + tc] = o;
  }
}

// ---------------- per-row stats reduce: 64 partials -> (max, 1/sum) ----------------
__global__ __launch_bounds__(256) void reduce_stats(const float2* __restrict__ pb,
                                                    float2* __restrict__ st) {
  const int row = blockIdx.x * 4 + (threadIdx.x >> 6);
  const int lane = threadIdx.x & 63;
  float2 p = pb[(long)row * 64 + lane];
  float mx = p.x;
  for (int off = 1; off < 64; off <<= 1) mx = fmaxf(mx, __shfl_xor(mx, off));
  float s = p.y * __expf(p.x - mx);
  for (int off = 1; off < 64; off <<= 1) s += __shfl_xor(s, off);
  if (!lane) st[row] = make_float2(mx, 1.f / s);
}

enum { EPI_F32 = 0, EPI_F16 = 1, EPI_PROJ = 2, EPI_GELU = 3, EPI_FINAL = 4 };

// ============ 256x256 8-phase GEMM (NT), for M=N=4096-class shapes ============
// R16 configuration (proven 54.5us). NEW: for EPI_F32 (scores), epilogue also
// emits per-wave row partials (max, sum-exp) into pb[row][bnblk*4+wc]:
// each row is held by a 16-lane lf-group (shfl_xor width 16); 4 wc-waves x
// 16 bn-blocks cover all 64 partials per row.
#define VM4 asm volatile("s_waitcnt vmcnt(4)" ::: "memory")
#define VM0 asm volatile("s_waitcnt vmcnt(0)" ::: "memory")
#define NOP (void)0

#define PH(MQ, NQ, RDA, ASP, RDB, BSP, STG, WAITC)                                 \
  {                                                                                \
    if (RDA) {                                                                     \
      _Pragma("unroll") for (int m = 0; m < 4; ++m) {                              \
        av[m][0] = *(const f16x8*)&(ASP)[arow + m * 1024 + x0];                    \
        av[m][1] = *(const f16x8*)&(ASP)[arow + m * 1024 + x1];                    \
      }                                                                            \
    }                                                                              \
    if (RDB) {                                                                     \
      _Pragma("unroll") for (int n = 0; n < 2; ++n) {                              \
        bv[n][0] = *(const f16x8*)&(BSP)[brow + n * 1024 + x0];                    \
        bv[n][1] = *(const f16x8*)&(BSP)[brow + n * 1024 + x1];                    \
      }                                                                            \
    }                                                                              \
    STG;                                                                           \
    __builtin_amdgcn_sched_barrier(0);                                             \
    WAITC;                                                                         \
    __builtin_amdgcn_s_barrier();                                                  \
    __builtin_amdgcn_s_setprio(1);                                                 \
    _Pragma("unroll") for (int m = 0; m < 4; ++m)                                  \
      _Pragma("unroll") for (int n = 0; n < 2; ++n)                                \
        _Pragma("unroll") for (int kk = 0; kk < 2; ++kk)                           \
          acc[MQ][NQ][m][n] = __builtin_amdgcn_mfma_f32_16x16x32_f16(              \
              av[m][kk], bv[n][kk], acc[MQ][NQ][m][n], 0, 0, 0);                   \
    __builtin_amdgcn_s_setprio(0);                                                 \
    __builtin_amdgcn_sched_barrier(0);                                             \
  }

template <int EPI>
__global__ __launch_bounds__(512) void gemm256(const f16* __restrict__ A,
                                               const f16* __restrict__ B, int K,
                                               void* __restrict__ Cout, int ldc,
                                               const float* __restrict__ bias,
                                               float2* __restrict__ pb) {
  __shared__ f16 As[4][128 * 64];
  __shared__ f16 Bs[4][128 * 64];
  const int tid = threadIdx.x;
  const int wid = tid >> 6, lane = tid & 63;
  const int wr = wid >> 2, wc = wid & 3;
  const int lr = lane & 15, lk4 = lane >> 4;
  const int swz = xcd_swz16();
  const long bm = (long)(swz >> 4) * 256, bn = (long)(swz & 15) * 256;
  const f16* Abase = A + bm * K;
  const f16* Bbase = B + bn * K;
  const int nkt = K >> 6;  // >= 4, even

  const int x0 = (lk4 ^ (lr & 7)) << 3;
  const int x1 = ((4 | lk4) ^ (lr & 7)) << 3;
  const int arow = (wr * 64 + lr) * 64;
  const int brow = (wc * 32 + lr) * 64;

  const int erow0 = tid >> 3;
  const long swo = (long)(((tid & 7) ^ (erow0 & 7)) << 3);
  const f16* sA0 = Abase + (long)erow0 * K + swo;
  const f16* sA1 = sA0 + (long)64 * K;
  const f16* sAh0 = sA0 + (long)128 * K;
  const f16* sAh1 = sA1 + (long)128 * K;
  const f16* sB0 = Bbase + (long)erow0 * K + swo;
  const f16* sB1 = sB0 + (long)64 * K;
  const f16* sBh0 = sB0 + (long)128 * K;
  const f16* sBh1 = sB1 + (long)128 * K;
  const int dlo = tid * 8, dhi = 4096 + tid * 8;

  auto stage2 = [&](const f16* s0, const f16* s1, int k0, f16* dst) {
    g2l16(s0 + k0, dst + dlo);
    g2l16(s1 + k0, dst + dhi);
  };

  f32x4 acc[2][2][4][2];
#pragma unroll
  for (int a = 0; a < 2; ++a)
#pragma unroll
    for (int b = 0; b < 2; ++b)
#pragma unroll
      for (int m = 0; m < 4; ++m)
#pragma unroll
        for (int n = 0; n < 2; ++n) acc[a][b][m][n] = f32x4{0.f, 0.f, 0.f, 0.f};

  f16x8 av[4][2], bv[2][2];  // persist across phases (register-cached fragments)

  stage2(sA0, sA1, 0, As[0]);
  stage2(sBh0, sBh1, 0, Bs[1]);
  stage2(sB0, sB1, 0, Bs[0]);
  stage2(sAh0, sAh1, 0, As[1]);
  stage2(sA0, sA1, 64, As[2]);
  stage2(sB0, sB1, 64, Bs[2]);
  __builtin_amdgcn_sched_barrier(0);
  VM4;
  __builtin_amdgcn_s_barrier();
  __builtin_amdgcn_sched_barrier(0);

  int t = 0;
  for (; t <= nkt - 4; t += 2) {
    PH(0, 1, 1, As[0], 1, Bs[1], stage2(sBh0, sBh1, (t + 1) * 64, Bs[3]), NOP)
    PH(0, 0, 0, As[0], 1, Bs[0], stage2(sAh0, sAh1, (t + 1) * 64, As[3]), NOP)
    PH(1, 0, 1, As[1], 0, Bs[0], stage2(sA0, sA1, (t + 2) * 64, As[0]), NOP)
    PH(1, 1, 0, As[1], 1, Bs[1], stage2(sB0, sB1, (t + 2) * 64, Bs[0]), VM4)
    PH(0, 1, 1, As[2], 1, Bs[3], stage2(sBh0, sBh1, (t + 2) * 64, Bs[1]), NOP)
    PH(0, 0, 0, As[2], 1, Bs[2], stage2(sAh0, sAh1, (t + 2) * 64, As[1]), NOP)
    PH(1, 0, 1, As[3], 0, Bs[2], stage2(sA0, sA1, (t + 3) * 64, As[2]), NOP)
    PH(1, 1, 0, As[3], 1, Bs[3], stage2(sB0, sB1, (t + 3) * 64, Bs[2]), VM4)
  }
  PH(0, 1, 1, As[0], 1, Bs[1], stage2(sBh0, sBh1, (nkt - 1) * 64, Bs[3]), NOP)
  PH(0, 0, 0, As[0], 1, Bs[0], stage2(sAh0, sAh1, (nkt - 1) * 64, As[3]), NOP)
  PH(1, 0, 1, As[1], 0, Bs[0], NOP, NOP)
  PH(1, 1, 0, As[1], 1, Bs[1], NOP, VM0)
  PH(0, 1, 1, As[2], 1, Bs[3], NOP, NOP)
  PH(0, 0, 0, As[2], 1, Bs[2], NOP, NOP)
  PH(1, 0, 1, As[3], 0, Bs[2], NOP, NOP)
  PH(1, 1, 0, As[3], 1, Bs[3], NOP, NOP)

  // epilogue: C-write
  const int l4 = lane >> 4, lf = lane & 15;
#pragma unroll
  for (int mq = 0; mq < 2; ++mq)
#pragma unroll
    for (int nq = 0; nq < 2; ++nq)
#pragma unroll
      for (int m = 0; m < 4; ++m)
#pragma unroll
        for (int n = 0; n < 2; ++n) {
          const long r = bm + mq * 128 + wr * 64 + m * 16 + l4 * 4;
          const long cc = bn + nq * 128 + wc * 32 + n * 16 + lf;
          float bcol = 0.f;
          if (EPI == EPI_GELU) bcol = bias[cc];
#pragma unroll
          for (int q = 0; q < 4; ++q) {
            const long idx = (r + q) * ldc + cc;
            const float v = acc[mq][nq][m][n][q];
            if (EPI == EPI_F32) {
              ((float*)Cout)[idx] = v;
            } else {  // EPI_GELU
              const float h = v + bcol;
              ((f16*)Cout)[idx] = (f16)(0.5f * h * (1.f + erff(h * 0.70710678118654752f)));
            }
          }
        }

  // epilogue: per-wave softmax row partials (scores only)
  if (EPI == EPI_F32) {
#pragma unroll
    for (int mq = 0; mq < 2; ++mq)
#pragma unroll
      for (int m = 0; m < 4; ++m)
#pragma unroll
        for (int q = 0; q < 4; ++q) {
          const float v0 = acc[mq][0][m][0][q], v1 = acc[mq][0][m][1][q];
          const float v2 = acc[mq][1][m][0][q], v3 = acc[mq][1][m][1][q];
          float mx = fmaxf(fmaxf(v0, v1), fmaxf(v2, v3));
          for (int off = 1; off < 16; off <<= 1) mx = fmaxf(mx, __shfl_xor(mx, off, 16));
          float sm = __expf(v0 - mx) + __expf(v1 - mx) + __expf(v2 - mx) + __expf(v3 - mx);
          for (int off = 1; off < 16; off <<= 1) sm += __shfl_xor(sm, off, 16);
          if (lf == 0) {
            const long r = bm + mq * 128 + wr * 64 + m * 16 + l4 * 4 + q;
            pb[r * 64 + (swz & 15) * 4 + wc] = make_float2(mx, sm);
          }
        }
  }
}

// ---------------- 128xBN NT GEMM (2-phase dbuf + swizzle), for N=1024 shapes ----
template <int BN, int BK>
__device__ __forceinline__ void stage_tile(const f16* __restrict__ Arow,
                                           const f16* __restrict__ Brow, int K, int kt,
                                           int tid, f16* Asd, f16* Bsd) {
  constexpr int CH = BK / 8;  // 16B chunks per row
  const int k0 = kt * BK;
#pragma unroll
  for (int rr = 0; rr < 128 * CH / 256; ++rr) {
    int e = rr * 256 + tid;
    int row = e / CH, c = e % CH;
    int cs = c ^ (row & (CH - 1));
    g2l16(Arow + (long)row * K + k0 + cs * 8, Asd + e * 8);
  }
#pragma unroll
  for (int rr = 0; rr < BN * CH / 256; ++rr) {
    int e = rr * 256 + tid;
    int row = e / CH, c = e % CH;
    int cs = c ^ (row & (CH - 1));
    g2l16(Brow + (long)row * K + k0 + cs * 8, Bsd + e * 8);
  }
  __builtin_amdgcn_sched_barrier(0);
}

template <int NJ, int BK>
__device__ __forceinline__ void compute_tile(const f16* Asd, const f16* Bsd, int wm,
                                             int wn, int lr, int lk4,
                                             f32x4 (&acc)[4][NJ]) {
  constexpr int CH = BK / 8;
#pragma unroll
  for (int s = 0; s < BK / 32; ++s) {
    const int g = s * 4 + lk4;
    f16x8 av[4], bv[NJ];
#pragma unroll
    for (int i = 0; i < 4; i++) {
      int row = wm + i * 16 + lr;
      int slot = g ^ (row & (CH - 1));
      av[i] = *(const f16x8*)&Asd[row * BK + slot * 8];
    }
#pragma unroll
    for (int j = 0; j < NJ; j++) {
      int row = wn + j * 16 + lr;
      int slot = g ^ (row & (CH - 1));
      bv[j] = *(const f16x8*)&Bsd[row * BK + slot * 8];
    }
#pragma unroll
    for (int i = 0; i < 4; i++)
#pragma unroll
      for (int j = 0; j < NJ; j++)
        acc[i][j] = __builtin_amdgcn_mfma_f32_16x16x32_f16(av[i], bv[j], acc[i][j], 0, 0, 0);
  }
}

template <int EPI, int BN, int BK>
__global__ __launch_bounds__(256) void gemm_nt(const f16* __restrict__ A,
                                               const f16* __restrict__ B, int K,
                                               void* __restrict__ Cout, int ldc,
                                               const float* __restrict__ bias,
                                               const float* __restrict__ res) {
  constexpr int NJ = BN / 32;
  __shared__ f16 As0[128 * BK];
  __shared__ f16 As1[128 * BK];
  __shared__ f16 Bs0[BN * BK];
  __shared__ f16 Bs1[BN * BK];
  const int tid = threadIdx.x;
  const int wid = tid >> 6, lane = tid & 63;
  const int wm = (wid >> 1) * 64, wn = (wid & 1) * (BN / 2);
  const int lr = lane & 15, lk4 = lane >> 4;
  const int swz = xcd_swz16();  // grid is (16, 32): bn = swz&15, bm = swz>>4
  const long bm = (long)(swz >> 4) * 128;
  const long bn = (long)(swz & 15) * BN;

  f32x4 zero = {0.f, 0.f, 0.f, 0.f};
  f32x4 acc[4][NJ];
#pragma unroll
  for (int i = 0; i < 4; i++)
#pragma unroll
    for (int j = 0; j < NJ; j++) acc[i][j] = zero;

  const f16* Arow = A + bm * K;
  const f16* Brow = B + bn * K;
  const int nkt = K / BK;

  stage_tile<BN, BK>(Arow, Brow, K, 0, tid, As0, Bs0);
  __syncthreads();

  int kt = 0;
  for (; kt + 2 < nkt; kt += 2) {
    stage_tile<BN, BK>(Arow, Brow, K, kt + 1, tid, As1, Bs1);
    compute_tile<NJ, BK>(As0, Bs0, wm, wn, lr, lk4, acc);
    __syncthreads();
    stage_tile<BN, BK>(Arow, Brow, K, kt + 2, tid, As0, Bs0);
    compute_tile<NJ, BK>(As1, Bs1, wm, wn, lr, lk4, acc);
    __syncthreads();
  }
  stage_tile<BN, BK>(Arow, Brow, K, nkt - 1, tid, As1, Bs1);
  compute_tile<NJ, BK>(As0, Bs0, wm, wn, lr, lk4, acc);
  __syncthreads();
  compute_tile<NJ, BK>(As1, Bs1, wm, wn, lr, lk4, acc);

  const int r0 = (int)bm + wm + (lane >> 4) * 4;
  const int c0 = (int)bn + wn + (lane & 15);
#pragma unroll
  for (int i = 0; i < 4; i++) {
#pragma unroll
    for (int j = 0; j < NJ; j++) {
      const int c = c0 + j * 16;
      float bcol = 0.f;
      if (EPI == EPI_PROJ || EPI == EPI_GELU || EPI == EPI_FINAL) bcol = bias[c];
#pragma unroll
      for (int q = 0; q < 4; q++) {
        const int r = r0 + i * 16 + q;
        const long idx = (long)r * ldc + c;
        const float v = acc[i][j][q];
        if (EPI == EPI_F32) {
          ((float*)Cout)[idx] = v;
        } else if (EPI == EPI_F16) {
          ((f16*)Cout)[idx] = (f16)v;
        } else if (EPI == EPI_PROJ || EPI == EPI_FINAL) {
          ((float*)Cout)[idx] = v + bcol + res[idx];
        } else {
          const float h = v + bcol;
          const float gg = 0.5f * h * (1.f + erff(h * 0.70710678118654752f));
          ((f16*)Cout)[idx] = (f16)gg;
        }
      }
    }
  }
}

// ---------------- PV GEMM: o16[m,n] = sum_k softmax(S)[m,k] * vT[n,k] ----------------
// Fork of gemm_nt<EPI_F16,64,64>: A staged from f32 scores with on-the-fly
// exp(s - m)*rinv -> f16 (T14: issue loads early, exp+ds_write after compute).
__global__ __launch_bounds__(256) void gemm_pv(const float* __restrict__ S,
                                               const float2* __restrict__ st,
                                               const f16* __restrict__ B,
                                               f16* __restrict__ Cout) {
  constexpr int BK = 64, BN = 64, NJ = 2;
  __shared__ f16 As0[128 * 64];
  __shared__ f16 As1[128 * 64];
  __shared__ f16 Bs0[64 * 64];
  __shared__ f16 Bs1[64 * 64];
  const int tid = threadIdx.x;
  const int wid = tid >> 6, lane = tid & 63;
  const int wm = (wid >> 1) * 64, wn = (wid & 1) * 32;
  const int lr = lane & 15, lk4 = lane >> 4;
  const int swz = xcd_swz16();  // grid (16,32)
  const long bm = (long)(swz >> 4) * 128;
  const long bn = (long)(swz & 15) * BN;

  // staging maps: cs = (tid&7) ^ ((tid>>3)&7), rows rr*32 + (tid>>3)
  const int arow_ = tid >> 3, ac = tid & 7;
  const int cs = ac ^ (arow_ & 7);
  const float* srcA[4];
  float2 strow[4];
#pragma unroll
  for (int rr = 0; rr < 4; ++rr) {
    const int row = rr * 32 + arow_;
    srcA[rr] = S + (long)(bm + row) * NROW + cs * 8;
    strow[rr] = st[bm + row];
  }
  const f16* srcB0 = B + (long)(bn + arow_) * NROW + cs * 8;
  const f16* srcB1 = srcB0 + (long)32 * NROW;
  const int dB0 = tid * 8, dB1 = 2048 + tid * 8;

  auto stageB = [&](int k0, f16* Bsd) {
    g2l16(srcB0 + k0, Bsd + dB0);
    g2l16(srcB1 + k0, Bsd + dB1);
  };

  float4 ra[4][2];
  auto loadA = [&](int k0) {
#pragma unroll
    for (int rr = 0; rr < 4; ++rr) {
      ra[rr][0] = *(const float4*)(srcA[rr] + k0);
      ra[rr][1] = *(const float4*)(srcA[rr] + k0 + 4);
    }
  };
  auto writeA = [&](f16* Asd) {
#pragma unroll
    for (int rr = 0; rr < 4; ++rr) {
      const float m = strow[rr].x, ri = strow[rr].y;
      f16x8 h;
      h[0] = (f16)(__expf(ra[rr][0].x - m) * ri);
      h[1] = (f16)(__expf(ra[rr][0].y - m) * ri);
      h[2] = (f16)(__expf(ra[rr][0].z - m) * ri);
      h[3] = (f16)(__expf(ra[rr][0].w - m) * ri);
      h[4] = (f16)(__expf(ra[rr][1].x - m) * ri);
      h[5] = (f16)(__expf(ra[rr][1].y - m) * ri);
      h[6] = (f16)(__expf(ra[rr][1].z - m) * ri);
      h[7] = (f16)(__expf(ra[rr][1].w - m) * ri);
      *(f16x8*)&Asd[(rr * 256 + tid) * 8] = h;
    }
  };

  f32x4 acc[4][NJ];
#pragma unroll
  for (int i = 0; i < 4; i++)
#pragma unroll
    for (int j = 0; j < NJ; j++) acc[i][j] = f32x4{0.f, 0.f, 0.f, 0.f};

  const int nkt = NROW / BK;  // 64, even

  // prologue
  loadA(0);
  stageB(0, Bs0);
  __builtin_amdgcn_sched_barrier(0);
  asm volatile("s_waitcnt vmcnt(2)" ::: "memory");  // A loads done; B in flight
  writeA(As0);
  __syncthreads();

  int kt = 0;
  for (; kt + 2 < nkt; kt += 2) {
    loadA((kt + 1) * BK);
    stageB((kt + 1) * BK, Bs1);
    __builtin_amdgcn_sched_barrier(0);
    compute_tile<NJ, BK>(As0, Bs0, wm, wn, lr, lk4, acc);
    asm volatile("s_waitcnt vmcnt(2)" ::: "memory");
    writeA(As1);
    __syncthreads();
    loadA((kt + 2) * BK);
    stageB((kt + 2) * BK, Bs0);
    __builtin_amdgcn_sched_barrier(0);
    compute_tile<NJ, BK>(As1, Bs1, wm, wn, lr, lk4, acc);
    asm volatile("s_waitcnt vmcnt(2)" ::: "memory");
    writeA(As0);
    __syncthreads();
  }
  loadA((nkt - 1) * BK);
  stageB((nkt - 1) * BK, Bs1);
  __builtin_amdgcn_sched_barrier(0);
  compute_tile<NJ, BK>(As0, Bs0, wm, wn, lr, lk4, acc);
  asm volatile("s_waitcnt vmcnt(2)" ::: "memory");
  writeA(As1);
  __syncthreads();
  compute_tile<NJ, BK>(As1, Bs1, wm, wn, lr, lk4, acc);

  const int r0 = (int)bm + wm + (lane >> 4) * 4;
  const int c0 = (int)bn + wn + (lane & 15);
#pragma unroll
  for (int i = 0; i < 4; i++)
#pragma unroll
    for (int j = 0; j < NJ; j++)
#pragma unroll
      for (int q = 0; q < 4; q++) {
        const int r = r0 + i * 16 + q;
        Cout[(long)r * DMODEL + c0 + j * 16] = (f16)acc[i][j][q];
      }
}

// ---------------- host ----------------
extern "C" void kernel_launch(void* const* d_in, const int* in_sizes, int n_in,
                              void* d_out, int out_size, void* d_ws, size_t ws_size,
                              hipStream_t stream) {
  const float* x = (const float*)d_in[0];
  const float* x_encoder = (const float*)d_in[1];
  const float* pos = (const float*)d_in[2];
  const float* query_pos = (const float*)d_in[3];
  const float* Wp_sa = (const float*)d_in[4];
  const float* bp_sa = (const float*)d_in[5];
  const float* Wp_ca = (const float*)d_in[6];
  const float* bp_ca = (const float*)d_in[7];
  const float* W1 = (const float*)d_in[8];
  const float* b1 = (const float*)d_in[9];
  const float* W2 = (const float*)d_in[10];
  const float* b2 = (const float*)d_in[11];
  const float* g_sa = (const float*)d_in[12];
  const float* be_sa = (const float*)d_in[13];
  const float* g_ca = (const float*)d_in[14];
  const float* be_ca = (const float*)d_in[15];
  const float* g_ff = (const float*)d_in[16];
  const float* be_ff = (const float*)d_in[17];

  const size_t MB = 1024 * 1024;
  char* ws = (char*)d_ws;
  f16* wpsa16 = (f16*)(ws + 0 * MB);
  f16* wpca16 = (f16*)(ws + 2 * MB);
  f16* w116 = (f16*)(ws + 4 * MB);
  f16* w216 = (f16*)(ws + 12 * MB);
  f16* q16 = (f16*)(ws + 20 * MB);   // qk / q2 / n3
  f16* k16 = (f16*)(ws + 28 * MB);   // cross K
  f16* n16 = (f16*)(ws + 36 * MB);   // n1 / xe16
  f16* vT = (f16*)(ws + 44 * MB);    // V^T [1024][4096]
  f16* o16 = (f16*)(ws + 52 * MB);   // attn out
  float* x1 = (float*)(ws + 60 * MB);
  float* x2 = (float*)(ws + 76 * MB);
  float* scores = (float*)(ws + 92 * MB);  // 64MB fp32
  f16* h16 = (f16*)(ws + 92 * MB);         // reuses scores region after attn
  float2* pb = (float2*)(ws + 156 * MB);   // row partials [4096][64] = 2MB
  float2* st = (float2*)(ws + 158 * MB);   // row stats (m, rinv) = 32KB

  if (ws_size < (size_t)160 * MB) {
    fprintf(stderr, "kernel_launch: ws too small (%zu bytes, need %zu)\n", ws_size,
            (size_t)160 * MB);
    return;
  }

  // weight converts
  cvt_f32_f16<<<1024, 256, 0, stream>>>(Wp_sa, wpsa16, (long)DMODEL * DMODEL / 4);
  cvt_f32_f16<<<1024, 256, 0, stream>>>(Wp_ca, wpca16, (long)DMODEL * DMODEL / 4);
  cvt_f32_f16<<<2048, 256, 0, stream>>>(W1, w116, (long)DFF_ * DMODEL / 4);
  cvt_f32_f16<<<2048, 256, 0, stream>>>(W2, w216, (long)DMODEL * DFF_ / 4);

  // ---- self attention ----
  ln_row<<<NROW, 256, 0, stream>>>(x, g_sa, be_sa, pos, n16, q16);
  transpose_h<<<dim3(DMODEL / 64, NROW / 64), 256, 0, stream>>>(n16, vT, NROW, DMODEL);
  gemm256<EPI_F32><<<dim3(16, 16), 512, 0, stream>>>(q16, q16, DMODEL, scores, NROW,
                                                     nullptr, pb);
  reduce_stats<<<1024, 256, 0, stream>>>(pb, st);
  gemm_pv<<<dim3(16, 32), 256, 0, stream>>>(scores, st, vT, o16);
  gemm_nt<EPI_PROJ, 64, 64><<<dim3(16, 32), 256, 0, stream>>>(o16, wpsa16, DMODEL, x1,
                                                              DMODEL, bp_sa, x);

  // ---- cross attention ----
  ln_row<<<NROW, 256, 0, stream>>>(x1, g_ca, be_ca, query_pos, nullptr, q16);
  add_cvt<<<2048, 256, 0, stream>>>(x_encoder, pos, k16, n16, (long)NROW * DMODEL / 4);
  transpose_h<<<dim3(DMODEL / 64, NROW / 64), 256, 0, stream>>>(n16, vT, NROW, DMODEL);
  gemm256<EPI_F32><<<dim3(16, 16), 512, 0, stream>>>(q16, k16, DMODEL, scores, NROW,
                                                     nullptr, pb);
  reduce_stats<<<1024, 256, 0, stream>>>(pb, st);
  gemm_pv<<<dim3(16, 32), 256, 0, stream>>>(scores, st, vT, o16);
  gemm_nt<EPI_PROJ, 64, 64><<<dim3(16, 32), 256, 0, stream>>>(o16, wpca16, DMODEL, x2,
                                                              DMODEL, bp_ca, x1);

  // ---- feed-forward ----
  ln_row<<<NROW, 256, 0, stream>>>(x2, g_ff, be_ff, nullptr, nullptr, q16);
  gemm256<EPI_GELU><<<dim3(16, 16), 512, 0, stream>>>(q16, w116, DMODEL, h16, DFF_, b1,
                                                      nullptr);
  gemm_nt<EPI_FINAL, 64, 64><<<dim3(16, 32), 256, 0, stream>>>(h16, w216, DFF_,
                                                               (float*)d_out, DMODEL, b2,
                                                               x2);
}

// Round 18
// 385.899 us; speedup vs baseline: 1.2258x; 1.2258x over previous
//
#include <hip/hip_runtime.h>
#include <hip/hip_fp16.h>
#include <cstdint>
#include <cstdio>

#define NROW 4096
#define DMODEL 1024
#define DFF_ 4096

typedef _Float16 f16;
typedef _Float16 f16x4 __attribute__((ext_vector_type(4)));
typedef _Float16 f16x8 __attribute__((ext_vector_type(8)));
typedef float f32x4 __attribute__((ext_vector_type(4)));

__device__ __forceinline__ void g2l16(const void* g, void* l) {
  __builtin_amdgcn_global_load_lds((const __attribute__((address_space(1))) void*)g,
                                   (__attribute__((address_space(3))) void*)l,
                                   16, 0, 0);
}

// Bijective XCD-chunked block swizzle (T1). Requires nwg%8==0.
__device__ __forceinline__ int xcd_swz16() {
  const int bid = blockIdx.y * gridDim.x + blockIdx.x;
  const int nwg = gridDim.x * gridDim.y;
  return (bid & 7) * (nwg >> 3) + (bid >> 3);
}

// ---------------- elementwise converts ----------------
__global__ __launch_bounds__(256) void cvt_f32_f16(const float* __restrict__ in,
                                                   f16* __restrict__ out, long n4) {
  for (long i = (long)blockIdx.x * blockDim.x + threadIdx.x; i < n4;
       i += (long)gridDim.x * blockDim.x) {
    float4 a = ((const float4*)in)[i];
    f16x4 h = {(f16)a.x, (f16)a.y, (f16)a.z, (f16)a.w};
    ((f16x4*)out)[i] = h;
  }
}

// k16 = f16(xe + pos); xe16 = f16(xe)
__global__ __launch_bounds__(256) void add_cvt(const float* __restrict__ xe,
                                               const float* __restrict__ pos,
                                               f16* __restrict__ k16,
                                               f16* __restrict__ xe16, long n4) {
  for (long i = (long)blockIdx.x * blockDim.x + threadIdx.x; i < n4;
       i += (long)gridDim.x * blockDim.x) {
    float4 a = ((const float4*)xe)[i];
    float4 p = ((const float4*)pos)[i];
    f16x4 k = {(f16)(a.x + p.x), (f16)(a.y + p.y), (f16)(a.z + p.z), (f16)(a.w + p.w)};
    f16x4 v = {(f16)a.x, (f16)a.y, (f16)a.z, (f16)a.w};
    ((f16x4*)k16)[i] = k;
    ((f16x4*)xe16)[i] = v;
  }
}

// ---------------- layernorm (one block per row of 1024) ----------------
__global__ __launch_bounds__(256) void ln_row(const float* __restrict__ x,
                                              const float* __restrict__ g,
                                              const float* __restrict__ b,
                                              const float* __restrict__ pos,
                                              f16* __restrict__ nout,
                                              f16* __restrict__ qout) {
  const int row = blockIdx.x, tid = threadIdx.x;
  const float4 xv = ((const float4*)(x + (long)row * DMODEL))[tid];
  float s = xv.x + xv.y + xv.z + xv.w;
  float ss = xv.x * xv.x + xv.y * xv.y + xv.z * xv.z + xv.w * xv.w;
  for (int o = 32; o; o >>= 1) { s += __shfl_xor(s, o); ss += __shfl_xor(ss, o); }
  __shared__ float rs[4], rss[4];
  const int wid = tid >> 6, lane = tid & 63;
  if (!lane) { rs[wid] = s; rss[wid] = ss; }
  __syncthreads();
  s = rs[0] + rs[1] + rs[2] + rs[3];
  ss = rss[0] + rss[1] + rss[2] + rss[3];
  const float mean = s * (1.f / DMODEL);
  const float var = ss * (1.f / DMODEL) - mean * mean;
  const float rstd = rsqrtf(var + 1e-5f);
  const float4 gv = ((const float4*)g)[tid];
  const float4 bv = ((const float4*)b)[tid];
  float4 nv;
  nv.x = (xv.x - mean) * rstd * gv.x + bv.x;
  nv.y = (xv.y - mean) * rstd * gv.y + bv.y;
  nv.z = (xv.z - mean) * rstd * gv.z + bv.z;
  nv.w = (xv.w - mean) * rstd * gv.w + bv.w;
  if (nout) {
    f16x4 h = {(f16)nv.x, (f16)nv.y, (f16)nv.z, (f16)nv.w};
    *(f16x4*)&nout[(long)row * DMODEL + tid * 4] = h;
  }
  float4 pv = {0.f, 0.f, 0.f, 0.f};
  if (pos) pv = ((const float4*)(pos + (long)row * DMODEL))[tid];
  f16x4 q = {(f16)(nv.x + pv.x), (f16)(nv.y + pv.y), (f16)(nv.z + pv.z), (f16)(nv.w + pv.w)};
  *(f16x4*)&qout[(long)row * DMODEL + tid * 4] = q;
}

// ---------------- row softmax (4096 cols), fp32 in -> fp16 out ----------------
__global__ __launch_bounds__(256) void softmax_row(const float* __restrict__ S,
                                                   f16* __restrict__ P) {
  const int row = blockIdx.x, tid = threadIdx.x;
  const float4* Sr = (const float4*)(S + (long)row * NROW);
  float4 v[4];
  float m = -1e30f;
#pragma unroll
  for (int i = 0; i < 4; i++) {
    v[i] = Sr[tid + i * 256];
    m = fmaxf(m, fmaxf(fmaxf(v[i].x, v[i].y), fmaxf(v[i].z, v[i].w)));
  }
  for (int o = 32; o; o >>= 1) m = fmaxf(m, __shfl_xor(m, o));
  __shared__ float red[4], red2[4];
  const int wid = tid >> 6, lane = tid & 63;
  if (!lane) red[wid] = m;
  __syncthreads();
  m = fmaxf(fmaxf(red[0], red[1]), fmaxf(red[2], red[3]));
  float sum = 0.f;
#pragma unroll
  for (int i = 0; i < 4; i++) {
    v[i].x = __expf(v[i].x - m); v[i].y = __expf(v[i].y - m);
    v[i].z = __expf(v[i].z - m); v[i].w = __expf(v[i].w - m);
    sum += v[i].x + v[i].y + v[i].z + v[i].w;
  }
  for (int o = 32; o; o >>= 1) sum += __shfl_xor(sum, o);
  if (!lane) red2[wid] = sum;
  __syncthreads();
  sum = red2[0] + red2[1] + red2[2] + red2[3];
  const float r = 1.f / sum;
  f16* Pr = P + (long)row * NROW;
#pragma unroll
  for (int i = 0; i < 4; i++) {
    f16x4 h = {(f16)(v[i].x * r), (f16)(v[i].y * r), (f16)(v[i].z * r), (f16)(v[i].w * r)};
    *(f16x4*)&Pr[(tid + i * 256) * 4] = h;
  }
}

// ---------------- fp16 transpose: in [R][C] -> out [C][R], 64x64 tiles ----------------
__global__ __launch_bounds__(256) void transpose_h(const f16* __restrict__ in,
                                                   f16* __restrict__ out, int R, int C) {
  __shared__ f16 t[64][72];
  const int tid = threadIdx.x;
  const int r0 = blockIdx.y * 64, c0 = blockIdx.x * 64;
  const int tr = tid >> 4, tc = (tid & 15) * 4;
#pragma unroll
  for (int rr = 0; rr < 4; rr++) {
    int row = rr * 16 + tr;
    f16x4 v = *(const f16x4*)&in[(long)(r0 + row) * C + c0 + tc];
    *(f16x4*)&t[row][tc] = v;
  }
  __syncthreads();
#pragma unroll
  for (int rr = 0; rr < 4; rr++) {
    int row = rr * 16 + tr;
    f16x4 o = {t[tc + 0][row], t[tc + 1][row], t[tc + 2][row], t[tc + 3][row]};
    *(f16x4*)&out[(long)(c0 + row) * R + r0 + tc] = o;
  }
}

enum { EPI_F32 = 0, EPI_F16 = 1, EPI_PROJ = 2, EPI_GELU = 3, EPI_FINAL = 4 };

// ============ 256x256 8-phase GEMM (NT), for M=N=4096-class shapes ============
// R10/R16 configuration (best measured: 54.5us/dispatch, no spill):
//  - register-cached fragments read IN-phase, 28 ds_read_b128/tile
//  - ONE barrier per phase (post-vmcnt); sched_barrier(0) fences
//  - hoisted ds_read addressing + hoisted per-thread staging pointers
//  - VM4 once per tile (2 half-tiles stay in flight); chunk^row&7 swizzle
//  - XCD-chunked block swizzle; setprio(1) around MFMA cluster
// (Read-early pipeline R11-R15: blocked by 128-VGPR allocator cap -> spills.
//  Softmax-fusion R17: 16x redundant exp made PV VALU-bound -> reverted.)
#define VM4 asm volatile("s_waitcnt vmcnt(4)" ::: "memory")
#define VM0 asm volatile("s_waitcnt vmcnt(0)" ::: "memory")
#define NOP (void)0

#define PH(MQ, NQ, RDA, ASP, RDB, BSP, STG, WAITC)                                 \
  {                                                                                \
    if (RDA) {                                                                     \
      _Pragma("unroll") for (int m = 0; m < 4; ++m) {                              \
        av[m][0] = *(const f16x8*)&(ASP)[arow + m * 1024 + x0];                    \
        av[m][1] = *(const f16x8*)&(ASP)[arow + m * 1024 + x1];                    \
      }                                                                            \
    }                                                                              \
    if (RDB) {                                                                     \
      _Pragma("unroll") for (int n = 0; n < 2; ++n) {                              \
        bv[n][0] = *(const f16x8*)&(BSP)[brow + n * 1024 + x0];                    \
        bv[n][1] = *(const f16x8*)&(BSP)[brow + n * 1024 + x1];                    \
      }                                                                            \
    }                                                                              \
    STG;                                                                           \
    __builtin_amdgcn_sched_barrier(0);                                             \
    WAITC;                                                                         \
    __builtin_amdgcn_s_barrier();                                                  \
    __builtin_amdgcn_s_setprio(1);                                                 \
    _Pragma("unroll") for (int m = 0; m < 4; ++m)                                  \
      _Pragma("unroll") for (int n = 0; n < 2; ++n)                                \
        _Pragma("unroll") for (int kk = 0; kk < 2; ++kk)                           \
          acc[MQ][NQ][m][n] = __builtin_amdgcn_mfma_f32_16x16x32_f16(              \
              av[m][kk], bv[n][kk], acc[MQ][NQ][m][n], 0, 0, 0);                   \
    __builtin_amdgcn_s_setprio(0);                                                 \
    __builtin_amdgcn_sched_barrier(0);                                             \
  }

template <int EPI>
__global__ __launch_bounds__(512) void gemm256(const f16* __restrict__ A,
                                               const f16* __restrict__ B, int K,
                                               void* __restrict__ Cout, int ldc,
                                               const float* __restrict__ bias) {
  __shared__ f16 As[4][128 * 64];
  __shared__ f16 Bs[4][128 * 64];
  const int tid = threadIdx.x;
  const int wid = tid >> 6, lane = tid & 63;
  const int wr = wid >> 2, wc = wid & 3;
  const int lr = lane & 15, lk4 = lane >> 4;
  const int swz = xcd_swz16();
  const long bm = (long)(swz >> 4) * 256, bn = (long)(swz & 15) * 256;
  const f16* Abase = A + bm * K;
  const f16* Bbase = B + bn * K;
  const int nkt = K >> 6;  // >= 4, even

  // hoisted ds_read addressing (elements; m/n/slot become immediates)
  const int x0 = (lk4 ^ (lr & 7)) << 3;
  const int x1 = ((4 | lk4) ^ (lr & 7)) << 3;
  const int arow = (wr * 64 + lr) * 64;
  const int brow = (wc * 32 + lr) * 64;

  // hoisted staging sources: per-thread rows erow0 / erow0+64, chunk-swizzled
  const int erow0 = tid >> 3;
  const long swo = (long)(((tid & 7) ^ (erow0 & 7)) << 3);
  const f16* sA0 = Abase + (long)erow0 * K + swo;
  const f16* sA1 = sA0 + (long)64 * K;
  const f16* sAh0 = sA0 + (long)128 * K;
  const f16* sAh1 = sA1 + (long)128 * K;
  const f16* sB0 = Bbase + (long)erow0 * K + swo;
  const f16* sB1 = sB0 + (long)64 * K;
  const f16* sBh0 = sB0 + (long)128 * K;
  const f16* sBh1 = sB1 + (long)128 * K;
  const int dlo = tid * 8, dhi = 4096 + tid * 8;

  auto stage2 = [&](const f16* s0, const f16* s1, int k0, f16* dst) {
    g2l16(s0 + k0, dst + dlo);
    g2l16(s1 + k0, dst + dhi);
  };

  f32x4 acc[2][2][4][2];
#pragma unroll
  for (int a = 0; a < 2; ++a)
#pragma unroll
    for (int b = 0; b < 2; ++b)
#pragma unroll
      for (int m = 0; m < 4; ++m)
#pragma unroll
        for (int n = 0; n < 2; ++n) acc[a][b][m][n] = f32x4{0.f, 0.f, 0.f, 0.f};

  f16x8 av[4][2], bv[2][2];  // persist across phases (register-cached fragments)

  // prologue: tile0's 4 halves + A0(1),B0(1); VM4 -> tile0 landed, 2 in flight
  stage2(sA0, sA1, 0, As[0]);
  stage2(sBh0, sBh1, 0, Bs[1]);
  stage2(sB0, sB1, 0, Bs[0]);
  stage2(sAh0, sAh1, 0, As[1]);
  stage2(sA0, sA1, 64, As[2]);
  stage2(sB0, sB1, 64, Bs[2]);
  __builtin_amdgcn_sched_barrier(0);
  VM4;
  __builtin_amdgcn_s_barrier();
  __builtin_amdgcn_sched_barrier(0);

  int t = 0;
  for (; t <= nkt - 4; t += 2) {
    // tile t (even slots)
    PH(0, 1, 1, As[0], 1, Bs[1], stage2(sBh0, sBh1, (t + 1) * 64, Bs[3]), NOP)
    PH(0, 0, 0, As[0], 1, Bs[0], stage2(sAh0, sAh1, (t + 1) * 64, As[3]), NOP)
    PH(1, 0, 1, As[1], 0, Bs[0], stage2(sA0, sA1, (t + 2) * 64, As[0]), NOP)
    PH(1, 1, 0, As[1], 1, Bs[1], stage2(sB0, sB1, (t + 2) * 64, Bs[0]), VM4)
    // tile t+1 (odd slots)
    PH(0, 1, 1, As[2], 1, Bs[3], stage2(sBh0, sBh1, (t + 2) * 64, Bs[1]), NOP)
    PH(0, 0, 0, As[2], 1, Bs[2], stage2(sAh0, sAh1, (t + 2) * 64, As[1]), NOP)
    PH(1, 0, 1, As[3], 0, Bs[2], stage2(sA0, sA1, (t + 3) * 64, As[2]), NOP)
    PH(1, 1, 0, As[3], 1, Bs[3], stage2(sB0, sB1, (t + 3) * 64, Bs[2]), VM4)
  }
  // tail pair (nkt-2, nkt-1): only B1/A1 of last tile left to stage
  PH(0, 1, 1, As[0], 1, Bs[1], stage2(sBh0, sBh1, (nkt - 1) * 64, Bs[3]), NOP)
  PH(0, 0, 0, As[0], 1, Bs[0], stage2(sAh0, sAh1, (nkt - 1) * 64, As[3]), NOP)
  PH(1, 0, 1, As[1], 0, Bs[0], NOP, NOP)
  PH(1, 1, 0, As[1], 1, Bs[1], NOP, VM0)
  PH(0, 1, 1, As[2], 1, Bs[3], NOP, NOP)
  PH(0, 0, 0, As[2], 1, Bs[2], NOP, NOP)
  PH(1, 0, 1, As[3], 0, Bs[2], NOP, NOP)
  PH(1, 1, 0, As[3], 1, Bs[3], NOP, NOP)

  // epilogue
  const int l4 = lane >> 4, lf = lane & 15;
#pragma unroll
  for (int mq = 0; mq < 2; ++mq)
#pragma unroll
    for (int nq = 0; nq < 2; ++nq)
#pragma unroll
      for (int m = 0; m < 4; ++m)
#pragma unroll
        for (int n = 0; n < 2; ++n) {
          const long r = bm + mq * 128 + wr * 64 + m * 16 + l4 * 4;
          const long cc = bn + nq * 128 + wc * 32 + n * 16 + lf;
          float bcol = 0.f;
          if (EPI == EPI_GELU) bcol = bias[cc];
#pragma unroll
          for (int q = 0; q < 4; ++q) {
            const long idx = (r + q) * ldc + cc;
            const float v = acc[mq][nq][m][n][q];
            if (EPI == EPI_F32) {
              ((float*)Cout)[idx] = v;
            } else {  // EPI_GELU
              const float h = v + bcol;
              ((f16*)Cout)[idx] = (f16)(0.5f * h * (1.f + erff(h * 0.70710678118654752f)));
            }
          }
        }
}

// ---------------- 128xBN NT GEMM (2-phase dbuf + swizzle), for N=1024 shapes ----
template <int BN, int BK>
__device__ __forceinline__ void stage_tile(const f16* __restrict__ Arow,
                                           const f16* __restrict__ Brow, int K, int kt,
                                           int tid, f16* Asd, f16* Bsd) {
  constexpr int CH = BK / 8;  // 16B chunks per row
  const int k0 = kt * BK;
#pragma unroll
  for (int rr = 0; rr < 128 * CH / 256; ++rr) {
    int e = rr * 256 + tid;
    int row = e / CH, c = e % CH;
    int cs = c ^ (row & (CH - 1));
    g2l16(Arow + (long)row * K + k0 + cs * 8, Asd + e * 8);
  }
#pragma unroll
  for (int rr = 0; rr < BN * CH / 256; ++rr) {
    int e = rr * 256 + tid;
    int row = e / CH, c = e % CH;
    int cs = c ^ (row & (CH - 1));
    g2l16(Brow + (long)row * K + k0 + cs * 8, Bsd + e * 8);
  }
  __builtin_amdgcn_sched_barrier(0);
}

template <int NJ, int BK>
__device__ __forceinline__ void compute_tile(const f16* Asd, const f16* Bsd, int wm,
                                             int wn, int lr, int lk4,
                                             f32x4 (&acc)[4][NJ]) {
  constexpr int CH = BK / 8;
#pragma unroll
  for (int s = 0; s < BK / 32; ++s) {
    const int g = s * 4 + lk4;
    f16x8 av[4], bv[NJ];
#pragma unroll
    for (int i = 0; i < 4; i++) {
      int row = wm + i * 16 + lr;
      int slot = g ^ (row & (CH - 1));
      av[i] = *(const f16x8*)&Asd[row * BK + slot * 8];
    }
#pragma unroll
    for (int j = 0; j < NJ; j++) {
      int row = wn + j * 16 + lr;
      int slot = g ^ (row & (CH - 1));
      bv[j] = *(const f16x8*)&Bsd[row * BK + slot * 8];
    }
#pragma unroll
    for (int i = 0; i < 4; i++)
#pragma unroll
      for (int j = 0; j < NJ; j++)
        acc[i][j] = __builtin_amdgcn_mfma_f32_16x16x32_f16(av[i], bv[j], acc[i][j], 0, 0, 0);
  }
}

template <int EPI, int BN, int BK>
__global__ __launch_bounds__(256) void gemm_nt(const f16* __restrict__ A,
                                               const f16* __restrict__ B, int K,
                                               void* __restrict__ Cout, int ldc,
                                               const float* __restrict__ bias,
                                               const float* __restrict__ res) {
  constexpr int NJ = BN / 32;
  __shared__ f16 As0[128 * BK];
  __shared__ f16 As1[128 * BK];
  __shared__ f16 Bs0[BN * BK];
  __shared__ f16 Bs1[BN * BK];
  const int tid = threadIdx.x;
  const int wid = tid >> 6, lane = tid & 63;
  const int wm = (wid >> 1) * 64, wn = (wid & 1) * (BN / 2);
  const int lr = lane & 15, lk4 = lane >> 4;
  const int swz = xcd_swz16();  // grid is (16, 32): bn = swz&15, bm = swz>>4
  const long bm = (long)(swz >> 4) * 128;
  const long bn = (long)(swz & 15) * BN;

  f32x4 zero = {0.f, 0.f, 0.f, 0.f};
  f32x4 acc[4][NJ];
#pragma unroll
  for (int i = 0; i < 4; i++)
#pragma unroll
    for (int j = 0; j < NJ; j++) acc[i][j] = zero;

  const f16* Arow = A + bm * K;
  const f16* Brow = B + bn * K;
  const int nkt = K / BK;

  stage_tile<BN, BK>(Arow, Brow, K, 0, tid, As0, Bs0);
  __syncthreads();

  int kt = 0;
  for (; kt + 2 < nkt; kt += 2) {
    stage_tile<BN, BK>(Arow, Brow, K, kt + 1, tid, As1, Bs1);
    compute_tile<NJ, BK>(As0, Bs0, wm, wn, lr, lk4, acc);
    __syncthreads();
    stage_tile<BN, BK>(Arow, Brow, K, kt + 2, tid, As0, Bs0);
    compute_tile<NJ, BK>(As1, Bs1, wm, wn, lr, lk4, acc);
    __syncthreads();
  }
  stage_tile<BN, BK>(Arow, Brow, K, nkt - 1, tid, As1, Bs1);
  compute_tile<NJ, BK>(As0, Bs0, wm, wn, lr, lk4, acc);
  __syncthreads();
  compute_tile<NJ, BK>(As1, Bs1, wm, wn, lr, lk4, acc);

  const int r0 = (int)bm + wm + (lane >> 4) * 4;
  const int c0 = (int)bn + wn + (lane & 15);
#pragma unroll
  for (int i = 0; i < 4; i++) {
#pragma unroll
    for (int j = 0; j < NJ; j++) {
      const int c = c0 + j * 16;
      float bcol = 0.f;
      if (EPI == EPI_PROJ || EPI == EPI_GELU || EPI == EPI_FINAL) bcol = bias[c];
#pragma unroll
      for (int q = 0; q < 4; q++) {
        const int r = r0 + i * 16 + q;
        const long idx = (long)r * ldc + c;
        const float v = acc[i][j][q];
        if (EPI == EPI_F32) {
          ((float*)Cout)[idx] = v;
        } else if (EPI == EPI_F16) {
          ((f16*)Cout)[idx] = (f16)v;
        } else if (EPI == EPI_PROJ || EPI == EPI_FINAL) {
          ((float*)Cout)[idx] = v + bcol + res[idx];
        } else {
          const float h = v + bcol;
          const float gg = 0.5f * h * (1.f + erff(h * 0.70710678118654752f));
          ((f16*)Cout)[idx] = (f16)gg;
        }
      }
    }
  }
}

// ---------------- host ----------------
extern "C" void kernel_launch(void* const* d_in, const int* in_sizes, int n_in,
                              void* d_out, int out_size, void* d_ws, size_t ws_size,
                              hipStream_t stream) {
  const float* x = (const float*)d_in[0];
  const float* x_encoder = (const float*)d_in[1];
  const float* pos = (const float*)d_in[2];
  const float* query_pos = (const float*)d_in[3];
  const float* Wp_sa = (const float*)d_in[4];
  const float* bp_sa = (const float*)d_in[5];
  const float* Wp_ca = (const float*)d_in[6];
  const float* bp_ca = (const float*)d_in[7];
  const float* W1 = (const float*)d_in[8];
  const float* b1 = (const float*)d_in[9];
  const float* W2 = (const float*)d_in[10];
  const float* b2 = (const float*)d_in[11];
  const float* g_sa = (const float*)d_in[12];
  const float* be_sa = (const float*)d_in[13];
  const float* g_ca = (const float*)d_in[14];
  const float* be_ca = (const float*)d_in[15];
  const float* g_ff = (const float*)d_in[16];
  const float* be_ff = (const float*)d_in[17];

  const size_t MB = 1024 * 1024;
  char* ws = (char*)d_ws;
  f16* wpsa16 = (f16*)(ws + 0 * MB);
  f16* wpca16 = (f16*)(ws + 2 * MB);
  f16* w116 = (f16*)(ws + 4 * MB);
  f16* w216 = (f16*)(ws + 12 * MB);
  f16* q16 = (f16*)(ws + 20 * MB);   // qk / q2 / n3
  f16* k16 = (f16*)(ws + 28 * MB);   // cross K
  f16* n16 = (f16*)(ws + 36 * MB);   // n1 / xe16
  f16* vT = (f16*)(ws + 44 * MB);    // V^T [1024][4096]
  f16* o16 = (f16*)(ws + 52 * MB);   // attn out
  float* x1 = (float*)(ws + 60 * MB);
  float* x2 = (float*)(ws + 76 * MB);
  float* scores = (float*)(ws + 92 * MB);  // 64MB fp32
  f16* h16 = (f16*)(ws + 92 * MB);         // reuses scores region after attn
  f16* P16 = (f16*)(ws + 156 * MB);        // 32MB fp16

  if (ws_size < (size_t)188 * MB) {
    fprintf(stderr, "kernel_launch: ws too small (%zu bytes, need %zu)\n", ws_size,
            (size_t)188 * MB);
    return;
  }

  // weight converts
  cvt_f32_f16<<<1024, 256, 0, stream>>>(Wp_sa, wpsa16, (long)DMODEL * DMODEL / 4);
  cvt_f32_f16<<<1024, 256, 0, stream>>>(Wp_ca, wpca16, (long)DMODEL * DMODEL / 4);
  cvt_f32_f16<<<2048, 256, 0, stream>>>(W1, w116, (long)DFF_ * DMODEL / 4);
  cvt_f32_f16<<<2048, 256, 0, stream>>>(W2, w216, (long)DMODEL * DFF_ / 4);

  // ---- self attention ----
  ln_row<<<NROW, 256, 0, stream>>>(x, g_sa, be_sa, pos, n16, q16);
  transpose_h<<<dim3(DMODEL / 64, NROW / 64), 256, 0, stream>>>(n16, vT, NROW, DMODEL);
  gemm256<EPI_F32><<<dim3(16, 16), 512, 0, stream>>>(q16, q16, DMODEL, scores, NROW,
                                                     nullptr);
  softmax_row<<<NROW, 256, 0, stream>>>(scores, P16);
  gemm_nt<EPI_F16, 64, 64><<<dim3(16, 32), 256, 0, stream>>>(P16, vT, NROW, o16, DMODEL,
                                                             nullptr, nullptr);
  gemm_nt<EPI_PROJ, 64, 64><<<dim3(16, 32), 256, 0, stream>>>(o16, wpsa16, DMODEL, x1,
                                                              DMODEL, bp_sa, x);

  // ---- cross attention ----
  ln_row<<<NROW, 256, 0, stream>>>(x1, g_ca, be_ca, query_pos, nullptr, q16);
  add_cvt<<<2048, 256, 0, stream>>>(x_encoder, pos, k16, n16, (long)NROW * DMODEL / 4);
  transpose_h<<<dim3(DMODEL / 64, NROW / 64), 256, 0, stream>>>(n16, vT, NROW, DMODEL);
  gemm256<EPI_F32><<<dim3(16, 16), 512, 0, stream>>>(q16, k16, DMODEL, scores, NROW,
                                                     nullptr);
  softmax_row<<<NROW, 256, 0, stream>>>(scores, P16);
  gemm_nt<EPI_F16, 64, 64><<<dim3(16, 32), 256, 0, stream>>>(P16, vT, NROW, o16, DMODEL,
                                                             nullptr, nullptr);
  gemm_nt<EPI_PROJ, 64, 64><<<dim3(16, 32), 256, 0, stream>>>(o16, wpca16, DMODEL, x2,
                                                              DMODEL, bp_ca, x1);

  // ---- feed-forward ----
  ln_row<<<NROW, 256, 0, stream>>>(x2, g_ff, be_ff, nullptr, nullptr, q16);
  gemm256<EPI_GELU><<<dim3(16, 16), 512, 0, stream>>>(q16, w116, DMODEL, h16, DFF_, b1);
  gemm_nt<EPI_FINAL, 64, 64><<<dim3(16, 32), 256, 0, stream>>>(h16, w216, DFF_,
                                                               (float*)d_out, DMODEL, b2,
                                                               x2);
}